// Round 7
// baseline (3547.131 us; speedup 1.0000x reference)
//
#include <hip/hip_runtime.h>

#define NN 200000
#define NE 600000
#define DD 128
#define DXX 3
#define DMM 256
#define NLVL 16
#define NBLK 256

// ---- workspace byte offsets (total ~108.6 MB) ----
#define OFF_H      0LL                      // float h[NN][128]         102,400,000
#define OFF_CSO    102400000LL              // int csr_off[NN+1]            800,016
#define OFF_DEG    103200016LL              // int deg[NN]                  800,000
#define OFF_CUR    104000016LL              // int cur[NN]                  800,000
#define OFF_CSRC   104800016LL              // int csr_src[NE]            2,400,000
#define OFF_BSUM   107200016LL              // int bsum[256]                  1,024
#define OFF_NLIST  107201040LL              // int node_list[NN]            800,000
#define OFF_WCT    108001040LL              // float WcT[128][384]          196,608
#define OFF_WHHT   108197648LL              // float whhT[128][384]         196,608
#define OFF_MB     108394256LL              // float mb[384]                  1,536
#define OFF_W1H    108395792LL              // _Float16 W1h[256][128]        65,536
#define OFF_W2H    108461328LL              // _Float16 W2h[256][256]       131,072
#define OFF_CNT    108592400LL              // int counters[128]                512
#define WS_NEEDED  108592912LL

// cnt layout: [0..15] node_cnt  [32..48] node_start(17)  [66..81] node_cur
//             [120] bar  [121] gen

typedef float    f32x4 __attribute__((ext_vector_type(4)));
typedef _Float16 f16x8 __attribute__((ext_vector_type(8)));

__device__ __forceinline__ float sigm(float x){
  x = fminf(fmaxf(x, -30.f), 30.f);
  return 1.f/(1.f + __expf(-x));
}
__device__ __forceinline__ float tanh_(float x){
  x = fminf(fmaxf(x, -15.f), 15.f);
  float e = __expf(2.f*x);
  return (e - 1.f)/(e + 1.f);
}

// h[v][d] = W_emd[d] + b_emd[d] for all v
__global__ void k_init_h(float* h, const float* W_emd, const float* b_emd){
  __shared__ float h0[DD];
  if (threadIdx.x < DD) h0[threadIdx.x] = W_emd[threadIdx.x] + b_emd[threadIdx.x];
  __syncthreads();
  const int tot = NN*DD/4;
  for (int i = blockIdx.x*blockDim.x + threadIdx.x; i < tot; i += gridDim.x*blockDim.x){
    int d0 = (i & 31)*4;
    ((float4*)h)[i] = make_float4(h0[d0], h0[d0+1], h0[d0+2], h0[d0+3]);
  }
}

// histogram nodes by level
__global__ void k_count(const int* fl, int* cnt){
  __shared__ int hn[NLVL];
  if (threadIdx.x < NLVL) hn[threadIdx.x] = 0;
  __syncthreads();
  for (int i = blockIdx.x*blockDim.x + threadIdx.x; i < NN; i += gridDim.x*blockDim.x)
    atomicAdd(&hn[fl[i]], 1);
  __syncthreads();
  if (threadIdx.x < NLVL && hn[threadIdx.x])
    atomicAdd(&cnt[threadIdx.x], hn[threadIdx.x]);
}

__global__ void k_scan(int* cnt){
  if (threadIdx.x == 0){
    int s = 0;
    for (int l=0;l<NLVL;l++){ cnt[32+l] = s; s += cnt[l]; }
    cnt[48] = s;
    for (int l=0;l<NLVL;l++) cnt[66+l] = 0;
  }
}

// counting-sort fill of node_list (LDS hist + one global atomic per tile,level)
#define FB 1024
__global__ __launch_bounds__(256) void k_fill_n(const int* fl, int* cnt, int* node_list){
  __shared__ int hist[NLVL], base[NLVL];
  const int nt = (NN + FB - 1)/FB;
  for (int tile = blockIdx.x; tile < nt; tile += gridDim.x){
    const int i0 = tile*FB;
    if (threadIdx.x < NLVL) hist[threadIdx.x] = 0;
    __syncthreads();
    int lv[4], rk[4];
    #pragma unroll
    for (int j=0;j<4;j++){
      int i = i0 + threadIdx.x + j*256;
      if (i < NN){
        int l = fl[i];
        lv[j] = l;
        rk[j] = atomicAdd(&hist[l], 1);
      } else lv[j] = -1;
    }
    __syncthreads();
    if (threadIdx.x < NLVL)
      base[threadIdx.x] = atomicAdd(&cnt[66+threadIdx.x], hist[threadIdx.x]);
    __syncthreads();
    #pragma unroll
    for (int j=0;j<4;j++){
      if (lv[j] >= 0){
        int i = i0 + threadIdx.x + j*256;
        node_list[cnt[32+lv[j]] + base[lv[j]] + rk[j]] = i;
      }
    }
    __syncthreads();
  }
}

// in-degree count
__global__ void k_deg(const int* dst, int* deg){
  for (int e = blockIdx.x*blockDim.x + threadIdx.x; e < NE; e += gridDim.x*blockDim.x)
    atomicAdd(&deg[dst[e]], 1);
}

// 3-phase exclusive scan of deg -> csr_off
#define SCB 1024
__global__ __launch_bounds__(1024) void k_cscan1(const int* deg, int* cso, int* bsum){
  __shared__ int sh[SCB];
  const int b = blockIdx.x, t = threadIdx.x;
  const int i = b*SCB + t;
  int v = (i < NN) ? deg[i] : 0;
  sh[t] = v;
  __syncthreads();
  for (int ofs=1; ofs<SCB; ofs<<=1){
    int add = (t >= ofs) ? sh[t-ofs] : 0;
    __syncthreads();
    sh[t] += add;
    __syncthreads();
  }
  if (i < NN) cso[i] = sh[t] - v;   // exclusive
  if (t == SCB-1) bsum[b] = sh[t];
}
__global__ void k_cscan2(int* bsum, int* cso, int nb){
  if (threadIdx.x == 0){
    int run = 0;
    for (int b=0;b<nb;b++){ int tmp = bsum[b]; bsum[b] = run; run += tmp; }
    cso[NN] = run;
  }
}
__global__ __launch_bounds__(1024) void k_cscan3(int* cso, const int* bsum){
  const int i = blockIdx.x*SCB + threadIdx.x;
  if (i < NN) cso[i] += bsum[blockIdx.x];
}

__global__ void k_csr_fill(const int* srcp, const int* dstp, const int* cso,
                           int* cur, int* csr_src){
  for (int e = blockIdx.x*blockDim.x + threadIdx.x; e < NE; e += gridDim.x*blockDim.x){
    int d = dstp[e];
    int p = atomicAdd(&cur[d], 1);
    csr_src[cso[d] + p] = srcp[e];
  }
}

// Precompute WcT[k][r] = sum_j w_ih[r][j]*W_aggr[j][k]; whhT; mb; fp16 W1/W2
__global__ void k_prep(const float* w_ih, const float* W_aggr, const float* b_aggr,
                       const float* w_hh, const float* W1, const float* W2,
                       float* WcT, float* whhT, float* mb, _Float16* W1h, _Float16* W2h){
  const int tid = blockIdx.x*blockDim.x + threadIdx.x;
  const int stride = gridDim.x*blockDim.x;
  for (int i = tid; i < 384*DD; i += stride){
    int r = i >> 7, k = i & (DD-1);
    float s = 0.f;
    for (int j=0;j<DD;j++) s += w_ih[r*(DD+DXX)+j]*W_aggr[j*DD+k];
    WcT[k*384 + r] = s;
  }
  for (int i = tid; i < 384*DD; i += stride){
    int r = i >> 7, k = i & (DD-1);
    whhT[k*384 + r] = w_hh[r*DD + k];
  }
  for (int i = tid; i < 384; i += stride){
    float s = 0.f;
    for (int j=0;j<DD;j++) s += w_ih[i*(DD+DXX)+j]*b_aggr[j];
    mb[i] = s;
  }
  for (int i = tid; i < DMM*DD;  i += stride) W1h[i] = (_Float16)W1[i];
  for (int i = tid; i < DMM*DMM; i += stride) W2h[i] = (_Float16)W2[i];
}

// device-wide barrier (all NBLK blocks resident, 1 per CU).
// release: syncthreads drains all waves' stores; thread0 fence does cache-wide wb.
// acquire: thread0 fence invalidates; extra all-thread fence after exit = belt+braces.
__device__ __forceinline__ void gbar(int* bar, int* gen){
  __syncthreads();
  if (threadIdx.x == 0){
    __threadfence();
    int g = __hip_atomic_load(gen, __ATOMIC_RELAXED, __HIP_MEMORY_SCOPE_AGENT);
    if (__hip_atomic_fetch_add(bar, 1, __ATOMIC_ACQ_REL, __HIP_MEMORY_SCOPE_AGENT) == NBLK-1){
      __hip_atomic_store(bar, 0, __ATOMIC_RELAXED, __HIP_MEMORY_SCOPE_AGENT);
      __hip_atomic_fetch_add(gen, 1, __ATOMIC_ACQ_REL, __HIP_MEMORY_SCOPE_AGENT);
    } else {
      while (__hip_atomic_load(gen, __ATOMIC_ACQUIRE, __HIP_MEMORY_SCOPE_AGENT) == g)
        __builtin_amdgcn_s_sleep(1);
    }
    __threadfence();
  }
  __syncthreads();
  __threadfence();   // all threads: invalidate before any post-barrier global read
}

// ---- persistent level loop: phase A (gather, pre-update h) | gbar | phase B (GRU)
// 512 threads = 2 tile-slots of 256; slot s handles tile blockIdx.x + s*NBLK.
// Tiles are block-owned, so gathered data stays in LDS across the barrier.
#define GTM 32
__global__ __launch_bounds__(512, 1) void k_levels(const int* cnt,
    const int* node_list, const int* cso, const int* csr_src,
    const float* x, const float* WcT, const float* whhT, const float* mb,
    const float* w_ih, const float* b_ih, const float* b_hh, float* h,
    int* bar, int* gen){
  __shared__ float s_l[2][GTM][DD+4];
  __shared__ float h_l[2][GTM][DD+4];
  __shared__ float x_l[2][GTM][4];
  __shared__ float deg_l[2][GTM];
  __shared__ int   vidx[2][GTM];
  __shared__ int   eoff[2][GTM], ecnt[2][GTM];
  const int slot = threadIdx.x >> 8;        // 0/1
  const int t    = threadIdx.x & 255;
  const int jt   = t & (DD-1);
  const int g    = t >> 7;

  for (int l = 1; l < NLVL; l++){
    const int n0 = cnt[32+l];
    const int na = cnt[32+l+1] - n0;
    const int ntiles = (na + GTM-1)/GTM;    // < 2*NBLK always (na ~12500)
    const int tile = blockIdx.x + slot*NBLK;
    const bool act = (tile < ntiles);
    const int tb = tile*GTM;

    // ---- phase A: gather (reads only pre-update h) ----
    if (t < GTM){
      int row = tb + t;
      int v = (act && row < na) ? node_list[n0 + row] : -1;
      vidx[slot][t] = v;
      int e0 = 0, e1 = 0;
      if (v >= 0){ e0 = cso[v]; e1 = cso[v+1]; }
      eoff[slot][t] = e0; ecnt[slot][t] = e1 - e0;
      deg_l[slot][t] = (float)(e1 - e0);
      for (int kx=0; kx<DXX; kx++) x_l[slot][t][kx] = (v >= 0) ? x[v*DXX + kx] : 0.f;
    }
    __syncthreads();
    {
      const int j = t >> 3, sub = t & 7;    // 8 threads/row, 16 dims each
      const int v = vidx[slot][j];
      float4 a0={0,0,0,0}, a1={0,0,0,0}, a2={0,0,0,0}, a3={0,0,0,0};
      float4 b0=a0, b1=a0, b2=a0, b3=a0;
      if (v >= 0){
        const float4* hv = (const float4*)(h + (size_t)v*DD + sub*16);
        b0 = hv[0]; b1 = hv[1]; b2 = hv[2]; b3 = hv[3];
        const int e0 = eoff[slot][j], n = ecnt[slot][j];
        for (int i = 0; i < n; i++){
          const float4* hs = (const float4*)(h + (size_t)csr_src[e0+i]*DD + sub*16);
          float4 c0 = hs[0], c1 = hs[1], c2 = hs[2], c3 = hs[3];
          a0.x+=c0.x; a0.y+=c0.y; a0.z+=c0.z; a0.w+=c0.w;
          a1.x+=c1.x; a1.y+=c1.y; a1.z+=c1.z; a1.w+=c1.w;
          a2.x+=c2.x; a2.y+=c2.y; a2.z+=c2.z; a2.w+=c2.w;
          a3.x+=c3.x; a3.y+=c3.y; a3.z+=c3.z; a3.w+=c3.w;
        }
      }
      *(float4*)&s_l[slot][j][sub*16]      = a0;
      *(float4*)&s_l[slot][j][sub*16 + 4]  = a1;
      *(float4*)&s_l[slot][j][sub*16 + 8]  = a2;
      *(float4*)&s_l[slot][j][sub*16 + 12] = a3;
      *(float4*)&h_l[slot][j][sub*16]      = b0;
      *(float4*)&h_l[slot][j][sub*16 + 4]  = b1;
      *(float4*)&h_l[slot][j][sub*16 + 8]  = b2;
      *(float4*)&h_l[slot][j][sub*16 + 12] = b3;
    }

    gbar(bar, gen);   // ALL gathers complete before ANY level-l update

    // ---- phase B: GRU from LDS ----
    if (act){
      float agr[16], agz[16], agn[16], ahr[16], ahz[16], ahn[16];
      #pragma unroll
      for (int n=0;n<16;n++){ agr[n]=0.f; agz[n]=0.f; agn[n]=0.f; ahr[n]=0.f; ahz[n]=0.f; ahn[n]=0.f; }

      #pragma unroll 2
      for (int k=0;k<DD;k++){
        float w1 = WcT[k*384 + jt];
        float w2 = WcT[k*384 + 128 + jt];
        float w3 = WcT[k*384 + 256 + jt];
        float u1 = whhT[k*384 + jt];
        float u2 = whhT[k*384 + 128 + jt];
        float u3 = whhT[k*384 + 256 + jt];
        #pragma unroll
        for (int n=0;n<16;n++){
          int node = 2*n + g;
          float sv = s_l[slot][node][k];
          float hv = h_l[slot][node][k];
          agr[n] = fmaf(w1, sv, agr[n]);
          agz[n] = fmaf(w2, sv, agz[n]);
          agn[n] = fmaf(w3, sv, agn[n]);
          ahr[n] = fmaf(u1, hv, ahr[n]);
          ahz[n] = fmaf(u2, hv, ahz[n]);
          ahn[n] = fmaf(u3, hv, ahn[n]);
        }
      }
      #pragma unroll
      for (int kx=0;kx<DXX;kx++){
        float wx1 = w_ih[jt*(DD+DXX) + DD + kx];
        float wx2 = w_ih[(128+jt)*(DD+DXX) + DD + kx];
        float wx3 = w_ih[(256+jt)*(DD+DXX) + DD + kx];
        #pragma unroll
        for (int n=0;n<16;n++){
          int node = 2*n + g;
          float xv = x_l[slot][node][kx];
          agr[n] = fmaf(wx1, xv, agr[n]);
          agz[n] = fmaf(wx2, xv, agz[n]);
          agn[n] = fmaf(wx3, xv, agn[n]);
        }
      }
      float bi1 = b_ih[jt], bi2 = b_ih[128+jt], bi3 = b_ih[256+jt];
      float bh1 = b_hh[jt], bh2 = b_hh[128+jt], bh3 = b_hh[256+jt];
      float m1 = mb[jt], m2 = mb[128+jt], m3 = mb[256+jt];
      #pragma unroll
      for (int n=0;n<16;n++){
        int node = 2*n + g;
        int v = vidx[slot][node];
        if (v < 0) continue;
        float dg = deg_l[slot][node];
        float gr = agr[n] + bi1 + dg*m1 + ahr[n] + bh1;
        float gz = agz[n] + bi2 + dg*m2 + ahz[n] + bh2;
        float rr = sigm(gr);
        float zz = sigm(gz);
        float gn = agn[n] + bi3 + dg*m3 + rr*(ahn[n] + bh3);
        float nv = tanh_(gn);
        float hv = h_l[slot][node][jt];
        __hip_atomic_store(&h[(size_t)v*DD + jt], (1.f - zz)*nv + zz*hv,
                           __ATOMIC_RELAXED, __HIP_MEMORY_SCOPE_AGENT);
      }
    }
    if (l < NLVL-1) gbar(bar, gen);   // level-l updates visible before level-l+1 gather
  }
}

// Persistent-weight MFMA MLP (unchanged from round 5)
__global__ __launch_bounds__(256, 1) void k_mlp_pw(const float* __restrict__ h,
    const _Float16* __restrict__ W1h, const float* __restrict__ b1,
    const _Float16* __restrict__ W2h, const float* __restrict__ b2,
    const float* __restrict__ W3, const float* __restrict__ b3,
    float* __restrict__ out){
  __shared__ _Float16 h1s[64*256];   // 32 KB, rows 512B, byte ^= (row&7)<<4
  __shared__ float red[4][64];
  const int t    = threadIdx.x;
  const int w    = t >> 6;
  const int lane = t & 63;
  const int c    = lane & 15;
  const int g    = lane >> 4;

  f16x8 w1f[4][4], w2f[4][8];
  #pragma unroll
  for (int n = 0; n < 4; n++){
    const _Float16* wp = W1h + ((4*w+n)*16 + c)*DD + 8*g;
    #pragma unroll
    for (int s = 0; s < 4; s++) w1f[n][s] = *(const f16x8*)(wp + s*32);
  }
  #pragma unroll
  for (int n = 0; n < 4; n++){
    const _Float16* wp = W2h + ((4*w+n)*16 + c)*DMM + 8*g;
    #pragma unroll
    for (int s = 0; s < 8; s++) w2f[n][s] = *(const f16x8*)(wp + s*32);
  }
  float bb1[4], bb2[4], w3v[4];
  #pragma unroll
  for (int n = 0; n < 4; n++){
    bb1[n] = b1[(4*w+n)*16 + c];
    bb2[n] = b2[(4*w+n)*16 + c];
    w3v[n] = W3[(4*w+n)*16 + c];
  }
  const float b3s = b3[0];

  for (int tile = blockIdx.x; tile < NN/64; tile += gridDim.x){
    const int base = tile*64;
    f16x8 a1[4][4];
    #pragma unroll
    for (int m = 0; m < 4; m++){
      const float* hp = h + (size_t)(base + m*16 + c)*DD + 8*g;
      #pragma unroll
      for (int s = 0; s < 4; s++){
        float4 u0 = *(const float4*)(hp + s*32);
        float4 u1 = *(const float4*)(hp + s*32 + 4);
        a1[m][s] = (f16x8){(_Float16)u0.x,(_Float16)u0.y,(_Float16)u0.z,(_Float16)u0.w,
                           (_Float16)u1.x,(_Float16)u1.y,(_Float16)u1.z,(_Float16)u1.w};
      }
    }
    f32x4 acc[4][4];
    #pragma unroll
    for (int m = 0; m < 4; m++)
      #pragma unroll
      for (int n = 0; n < 4; n++) acc[m][n] = (f32x4){0.f,0.f,0.f,0.f};
    #pragma unroll
    for (int m = 0; m < 4; m++)
      #pragma unroll
      for (int n = 0; n < 4; n++)
        #pragma unroll
        for (int s = 0; s < 4; s++)
          acc[m][n] = __builtin_amdgcn_mfma_f32_16x16x32_f16(a1[m][s], w1f[n][s], acc[m][n], 0, 0, 0);
    #pragma unroll
    for (int m = 0; m < 4; m++)
      #pragma unroll
      for (int n = 0; n < 4; n++)
        #pragma unroll
        for (int r = 0; r < 4; r++){
          int row = m*16 + 4*g + r;
          int off = (row*512 + ((4*w+n)*16 + c)*2) ^ ((row & 7) << 4);
          *(_Float16*)((char*)h1s + off) = (_Float16)fmaxf(acc[m][n][r] + bb1[n], 0.f);
        }
    __syncthreads();
    float p[4][4];
    #pragma unroll
    for (int m = 0; m < 4; m++)
      #pragma unroll
      for (int r = 0; r < 4; r++) p[m][r] = 0.f;
    #pragma unroll
    for (int m = 0; m < 4; m++){
      f16x8 a2[8];
      int row = m*16 + c;
      #pragma unroll
      for (int s = 0; s < 8; s++){
        int off = (row*512 + s*64 + g*16) ^ ((row & 7) << 4);
        a2[s] = *(const f16x8*)((const char*)h1s + off);
      }
      f32x4 acc2[4];
      #pragma unroll
      for (int n = 0; n < 4; n++) acc2[n] = (f32x4){0.f,0.f,0.f,0.f};
      #pragma unroll
      for (int n = 0; n < 4; n++)
        #pragma unroll
        for (int s = 0; s < 8; s++)
          acc2[n] = __builtin_amdgcn_mfma_f32_16x16x32_f16(a2[s], w2f[n][s], acc2[n], 0, 0, 0);
      #pragma unroll
      for (int n = 0; n < 4; n++)
        #pragma unroll
        for (int r = 0; r < 4; r++)
          p[m][r] = fmaf(fmaxf(acc2[n][r] + bb2[n], 0.f), w3v[n], p[m][r]);
    }
    #pragma unroll
    for (int msk = 1; msk < 16; msk <<= 1)
      #pragma unroll
      for (int m = 0; m < 4; m++)
        #pragma unroll
        for (int r = 0; r < 4; r++)
          p[m][r] += __shfl_xor(p[m][r], msk);
    if (c == 0){
      #pragma unroll
      for (int m = 0; m < 4; m++)
        #pragma unroll
        for (int r = 0; r < 4; r++)
          red[w][m*16 + 4*g + r] = p[m][r];
    }
    __syncthreads();
    if (t < 64)
      out[base + t] = red[0][t] + red[1][t] + red[2][t] + red[3][t] + b3s;
  }
}

extern "C" void kernel_launch(void* const* d_in, const int* in_sizes, int n_in,
                              void* d_out, int out_size, void* d_ws, size_t ws_size,
                              hipStream_t stream){
  if (ws_size < (size_t)WS_NEEDED) return;  // fail validation cleanly, don't fault
  const float* x      = (const float*)d_in[0];
  const int*   ei     = (const int*)  d_in[1];
  const int*   srcp   = ei;
  const int*   dstp   = ei + NE;
  const int*   fl     = (const int*)  d_in[2];
  const float* W_emd  = (const float*)d_in[3];
  const float* b_emd  = (const float*)d_in[4];
  const float* W_aggr = (const float*)d_in[5];
  const float* b_aggr = (const float*)d_in[6];
  const float* w_ih   = (const float*)d_in[7];
  const float* w_hh   = (const float*)d_in[8];
  const float* b_ih   = (const float*)d_in[9];
  const float* b_hh   = (const float*)d_in[10];
  const float* W1     = (const float*)d_in[11];
  const float* b1     = (const float*)d_in[12];
  const float* W2     = (const float*)d_in[13];
  const float* b2     = (const float*)d_in[14];
  const float* W3     = (const float*)d_in[15];
  const float* b3     = (const float*)d_in[16];

  char* ws = (char*)d_ws;
  float* h        = (float*)(ws + OFF_H);
  int*   cso      = (int*)  (ws + OFF_CSO);
  int*   deg      = (int*)  (ws + OFF_DEG);
  int*   cur      = (int*)  (ws + OFF_CUR);
  int*   csr_src  = (int*)  (ws + OFF_CSRC);
  int*   bsum     = (int*)  (ws + OFF_BSUM);
  int*   node_list= (int*)  (ws + OFF_NLIST);
  float* WcT      = (float*)(ws + OFF_WCT);
  float* whhT     = (float*)(ws + OFF_WHHT);
  float* mb       = (float*)(ws + OFF_MB);
  _Float16* W1h   = (_Float16*)(ws + OFF_W1H);
  _Float16* W2h   = (_Float16*)(ws + OFF_W2H);
  int*   cnt      = (int*)  (ws + OFF_CNT);
  float* outp     = (float*)d_out;

  const int nsb = (NN + SCB - 1)/SCB;   // 196 scan blocks

  hipMemsetAsync(ws + OFF_CNT, 0, 512, stream);
  hipMemsetAsync(ws + OFF_DEG, 0, 1600000, stream);   // deg + cur
  k_init_h<<<4096, 256, 0, stream>>>(h, W_emd, b_emd);
  k_count<<<1024, 256, 0, stream>>>(fl, cnt);
  k_scan<<<1, 64, 0, stream>>>(cnt);
  k_fill_n<<<196, 256, 0, stream>>>(fl, cnt, node_list);
  k_deg<<<1024, 256, 0, stream>>>(dstp, deg);
  k_cscan1<<<nsb, SCB, 0, stream>>>(deg, cso, bsum);
  k_cscan2<<<1, 64, 0, stream>>>(bsum, cso, nsb);
  k_cscan3<<<nsb, SCB, 0, stream>>>(cso, bsum);
  k_csr_fill<<<1024, 256, 0, stream>>>(srcp, dstp, cso, cur, csr_src);
  k_prep<<<256, 256, 0, stream>>>(w_ih, W_aggr, b_aggr, w_hh, W1, W2,
                                  WcT, whhT, mb, W1h, W2h);
  k_levels<<<NBLK, 512, 0, stream>>>(cnt, node_list, cso, csr_src, x,
                                     WcT, whhT, mb, w_ih, b_ih, b_hh, h,
                                     &cnt[120], &cnt[121]);
  k_mlp_pw<<<256, 256, 0, stream>>>(h, W1h, b1, W2h, b2, W3, b3, outp);
}

// Round 8
// 2639.169 us; speedup vs baseline: 1.3440x; 1.3440x over previous
//
#include <hip/hip_runtime.h>

#define NN 200000
#define NE 600000
#define DD 128
#define DXX 3
#define DMM 256
#define NLVL 16
#define NBLK 256

// ---- workspace byte offsets (total ~108.4 MB) ----
#define OFF_H      0LL                      // float h[NN][128]         102,400,000
#define OFF_CSO    102400000LL              // int csr_off[NN+1]            800,016
#define OFF_DEG    103200016LL              // int deg[NN]                  800,000
#define OFF_CUR    104000016LL              // int cur[NN]                  800,000
#define OFF_CSRC   104800016LL              // int csr_src[NE]            2,400,000
#define OFF_BSUM   107200016LL              // int bsum[256]                  1,024
#define OFF_NLIST  107201040LL              // int node_list[NN]            800,000
#define OFF_WCH    108001040LL              // _Float16 Wch[384][128]        98,304
#define OFF_WHH    108099344LL              // _Float16 whh_h[384][128]      98,304
#define OFF_MB     108197648LL              // float mb[384]                  1,536
#define OFF_W1H    108199184LL              // _Float16 W1h[256][128]        65,536
#define OFF_W2H    108264720LL              // _Float16 W2h[256][256]       131,072
#define OFF_CNT    108395792LL              // int counters[128]                512
#define WS_NEEDED  108396304LL

// cnt layout: [0..15] node_cnt  [32..48] node_start(17)  [66..81] node_cur
//             [120] bar  [121] gen

typedef float    f32x4 __attribute__((ext_vector_type(4)));
typedef _Float16 f16x8 __attribute__((ext_vector_type(8)));

__device__ __forceinline__ float sigm(float x){
  x = fminf(fmaxf(x, -30.f), 30.f);
  return 1.f/(1.f + __expf(-x));
}
__device__ __forceinline__ float tanh_(float x){
  x = fminf(fmaxf(x, -15.f), 15.f);
  float e = __expf(2.f*x);
  return (e - 1.f)/(e + 1.f);
}

// h[v][d] = W_emd[d] + b_emd[d] for all v
__global__ void k_init_h(float* h, const float* W_emd, const float* b_emd){
  __shared__ float h0[DD];
  if (threadIdx.x < DD) h0[threadIdx.x] = W_emd[threadIdx.x] + b_emd[threadIdx.x];
  __syncthreads();
  const int tot = NN*DD/4;
  for (int i = blockIdx.x*blockDim.x + threadIdx.x; i < tot; i += gridDim.x*blockDim.x){
    int d0 = (i & 31)*4;
    ((float4*)h)[i] = make_float4(h0[d0], h0[d0+1], h0[d0+2], h0[d0+3]);
  }
}

// histogram nodes by level
__global__ void k_count(const int* fl, int* cnt){
  __shared__ int hn[NLVL];
  if (threadIdx.x < NLVL) hn[threadIdx.x] = 0;
  __syncthreads();
  for (int i = blockIdx.x*blockDim.x + threadIdx.x; i < NN; i += gridDim.x*blockDim.x)
    atomicAdd(&hn[fl[i]], 1);
  __syncthreads();
  if (threadIdx.x < NLVL && hn[threadIdx.x])
    atomicAdd(&cnt[threadIdx.x], hn[threadIdx.x]);
}

__global__ void k_scan(int* cnt){
  if (threadIdx.x == 0){
    int s = 0;
    for (int l=0;l<NLVL;l++){ cnt[32+l] = s; s += cnt[l]; }
    cnt[48] = s;
    for (int l=0;l<NLVL;l++) cnt[66+l] = 0;
  }
}

// counting-sort fill of node_list (LDS hist + one global atomic per tile,level)
#define FB 1024
__global__ __launch_bounds__(256) void k_fill_n(const int* fl, int* cnt, int* node_list){
  __shared__ int hist[NLVL], base[NLVL];
  const int nt = (NN + FB - 1)/FB;
  for (int tile = blockIdx.x; tile < nt; tile += gridDim.x){
    const int i0 = tile*FB;
    if (threadIdx.x < NLVL) hist[threadIdx.x] = 0;
    __syncthreads();
    int lv[4], rk[4];
    #pragma unroll
    for (int j=0;j<4;j++){
      int i = i0 + threadIdx.x + j*256;
      if (i < NN){
        int l = fl[i];
        lv[j] = l;
        rk[j] = atomicAdd(&hist[l], 1);
      } else lv[j] = -1;
    }
    __syncthreads();
    if (threadIdx.x < NLVL)
      base[threadIdx.x] = atomicAdd(&cnt[66+threadIdx.x], hist[threadIdx.x]);
    __syncthreads();
    #pragma unroll
    for (int j=0;j<4;j++){
      if (lv[j] >= 0){
        int i = i0 + threadIdx.x + j*256;
        node_list[cnt[32+lv[j]] + base[lv[j]] + rk[j]] = i;
      }
    }
    __syncthreads();
  }
}

// in-degree count
__global__ void k_deg(const int* dst, int* deg){
  for (int e = blockIdx.x*blockDim.x + threadIdx.x; e < NE; e += gridDim.x*blockDim.x)
    atomicAdd(&deg[dst[e]], 1);
}

// 3-phase exclusive scan of deg -> csr_off
#define SCB 1024
__global__ __launch_bounds__(1024) void k_cscan1(const int* deg, int* cso, int* bsum){
  __shared__ int sh[SCB];
  const int b = blockIdx.x, t = threadIdx.x;
  const int i = b*SCB + t;
  int v = (i < NN) ? deg[i] : 0;
  sh[t] = v;
  __syncthreads();
  for (int ofs=1; ofs<SCB; ofs<<=1){
    int add = (t >= ofs) ? sh[t-ofs] : 0;
    __syncthreads();
    sh[t] += add;
    __syncthreads();
  }
  if (i < NN) cso[i] = sh[t] - v;   // exclusive
  if (t == SCB-1) bsum[b] = sh[t];
}
__global__ void k_cscan2(int* bsum, int* cso, int nb){
  if (threadIdx.x == 0){
    int run = 0;
    for (int b=0;b<nb;b++){ int tmp = bsum[b]; bsum[b] = run; run += tmp; }
    cso[NN] = run;
  }
}
__global__ __launch_bounds__(1024) void k_cscan3(int* cso, const int* bsum){
  const int i = blockIdx.x*SCB + threadIdx.x;
  if (i < NN) cso[i] += bsum[blockIdx.x];
}

__global__ void k_csr_fill(const int* srcp, const int* dstp, const int* cso,
                           int* cur, int* csr_src){
  for (int e = blockIdx.x*blockDim.x + threadIdx.x; e < NE; e += gridDim.x*blockDim.x){
    int d = dstp[e];
    int p = atomicAdd(&cur[d], 1);
    csr_src[cso[d] + p] = srcp[e];
  }
}

// Precompute Wch[r][k] = (fp16) sum_j w_ih[r][j]*W_aggr[j][k]; whh_h; mb; W1h/W2h
__global__ void k_prep(const float* w_ih, const float* W_aggr, const float* b_aggr,
                       const float* w_hh, const float* W1, const float* W2,
                       _Float16* Wch, _Float16* whh_h, float* mb,
                       _Float16* W1h, _Float16* W2h){
  const int tid = blockIdx.x*blockDim.x + threadIdx.x;
  const int stride = gridDim.x*blockDim.x;
  for (int i = tid; i < 384*DD; i += stride){
    int r = i >> 7, k = i & (DD-1);
    float s = 0.f;
    for (int j=0;j<DD;j++) s += w_ih[r*(DD+DXX)+j]*W_aggr[j*DD+k];
    Wch[i]   = (_Float16)s;        // [r][k] row-major
    whh_h[i] = (_Float16)w_hh[i];  // w_hh is [384][128] row-major
  }
  for (int i = tid; i < 384; i += stride){
    float s = 0.f;
    for (int j=0;j<DD;j++) s += w_ih[i*(DD+DXX)+j]*b_aggr[j];
    mb[i] = s;
  }
  for (int i = tid; i < DMM*DD;  i += stride) W1h[i] = (_Float16)W1[i];
  for (int i = tid; i < DMM*DMM; i += stride) W2h[i] = (_Float16)W2[i];
}

// device-wide barrier (all NBLK blocks resident, 1 per CU).
__device__ __forceinline__ void gbar(int* bar, int* gen){
  __syncthreads();
  if (threadIdx.x == 0){
    __threadfence();
    int g = __hip_atomic_load(gen, __ATOMIC_RELAXED, __HIP_MEMORY_SCOPE_AGENT);
    if (__hip_atomic_fetch_add(bar, 1, __ATOMIC_ACQ_REL, __HIP_MEMORY_SCOPE_AGENT) == NBLK-1){
      __hip_atomic_store(bar, 0, __ATOMIC_RELAXED, __HIP_MEMORY_SCOPE_AGENT);
      __hip_atomic_fetch_add(gen, 1, __ATOMIC_ACQ_REL, __HIP_MEMORY_SCOPE_AGENT);
    } else {
      while (__hip_atomic_load(gen, __ATOMIC_ACQUIRE, __HIP_MEMORY_SCOPE_AGENT) == g)
        __builtin_amdgcn_s_sleep(1);
    }
    __threadfence();
  }
  __syncthreads();
  __threadfence();   // all threads: invalidate before any post-barrier global read
}

// ---- persistent level loop, MFMA GRU.
// 512 thr / 8 waves; block owns ONE 64-node tile per level (<=256 tiles).
// Wave w owns hidden cols [16w,16w+16) of ALL 3 gates (B rows jo,128+jo,256+jo)
// -> gate combine is lane-local. Weights in registers for whole kernel.
// phase A (f32 CSR gather -> LDS) | gbar | phase B (MFMA + gates + store) | gbar
#define GT 64
__global__ __launch_bounds__(512, 2) void k_levels(const int* cnt,
    const int* node_list, const int* cso, const int* csr_src,
    const float* x, const _Float16* Wch, const _Float16* whh_h, const float* mb,
    const float* w_ih, const float* b_ih, const float* b_hh, float* h,
    int* bar, int* gen){
  __shared__ float s_l[GT][DD+4];
  __shared__ float h_l[GT][DD+4];
  __shared__ float x_l[GT][4];
  __shared__ float deg_l[GT];
  __shared__ int   vidx[GT], eoff[GT], ecnt[GT];
  const int t    = threadIdx.x;
  const int w    = t >> 6;
  const int lane = t & 63;
  const int c0   = lane & 15;
  const int g    = lane >> 4;
  const int jo   = w*16 + c0;

  // persistent weight fragments + per-lane scalars (loaded once)
  f16x8 wcf[3][4], whf[3][4];
  #pragma unroll
  for (int gate = 0; gate < 3; gate++){
    const _Float16* wp = Wch   + (size_t)(gate*128 + jo)*DD + 8*g;
    const _Float16* up = whh_h + (size_t)(gate*128 + jo)*DD + 8*g;
    #pragma unroll
    for (int ks = 0; ks < 4; ks++){
      wcf[gate][ks] = *(const f16x8*)(wp + ks*32);
      whf[gate][ks] = *(const f16x8*)(up + ks*32);
    }
  }
  float biv[3], bhv[3], mbv[3], wxv[3][3];
  #pragma unroll
  for (int gate = 0; gate < 3; gate++){
    biv[gate] = b_ih[gate*128 + jo];
    bhv[gate] = b_hh[gate*128 + jo];
    mbv[gate] = mb[gate*128 + jo];
    #pragma unroll
    for (int kx = 0; kx < 3; kx++)
      wxv[gate][kx] = w_ih[(size_t)(gate*128 + jo)*(DD+DXX) + DD + kx];
  }

  for (int l = 1; l < NLVL; l++){
    const int n0 = cnt[32+l];
    const int na = cnt[32+l+1] - n0;
    const int tb = blockIdx.x * GT;
    const bool act = (tb < na);

    // ---- phase A: gather (reads only pre-update h) ----
    if (t < GT){
      int row = tb + t;
      int v = (act && row < na) ? node_list[n0 + row] : -1;
      vidx[t] = v;
      int e0 = 0, e1 = 0;
      if (v >= 0){ e0 = cso[v]; e1 = cso[v+1]; }
      eoff[t] = e0; ecnt[t] = e1 - e0;
      deg_l[t] = (float)(e1 - e0);
      for (int kx=0; kx<DXX; kx++) x_l[t][kx] = (v >= 0) ? x[v*DXX + kx] : 0.f;
    }
    __syncthreads();
    {
      const int j = t >> 3, sub = t & 7;    // 8 threads/row, 16 dims each
      const int v = vidx[j];
      float4 a0={0,0,0,0}, a1={0,0,0,0}, a2={0,0,0,0}, a3={0,0,0,0};
      float4 b0=a0, b1=a0, b2=a0, b3=a0;
      if (v >= 0){
        const float4* hv = (const float4*)(h + (size_t)v*DD + sub*16);
        b0 = hv[0]; b1 = hv[1]; b2 = hv[2]; b3 = hv[3];
        const int e0 = eoff[j], n = ecnt[j];
        for (int i = 0; i < n; i++){
          const float4* hs = (const float4*)(h + (size_t)csr_src[e0+i]*DD + sub*16);
          float4 c0v = hs[0], c1v = hs[1], c2v = hs[2], c3v = hs[3];
          a0.x+=c0v.x; a0.y+=c0v.y; a0.z+=c0v.z; a0.w+=c0v.w;
          a1.x+=c1v.x; a1.y+=c1v.y; a1.z+=c1v.z; a1.w+=c1v.w;
          a2.x+=c2v.x; a2.y+=c2v.y; a2.z+=c2v.z; a2.w+=c2v.w;
          a3.x+=c3v.x; a3.y+=c3v.y; a3.z+=c3v.z; a3.w+=c3v.w;
        }
      }
      *(float4*)&s_l[j][sub*16]      = a0;
      *(float4*)&s_l[j][sub*16 + 4]  = a1;
      *(float4*)&s_l[j][sub*16 + 8]  = a2;
      *(float4*)&s_l[j][sub*16 + 12] = a3;
      *(float4*)&h_l[j][sub*16]      = b0;
      *(float4*)&h_l[j][sub*16 + 4]  = b1;
      *(float4*)&h_l[j][sub*16 + 8]  = b2;
      *(float4*)&h_l[j][sub*16 + 12] = b3;
    }

    gbar(bar, gen);   // ALL gathers complete before ANY level-l update

    // ---- phase B: MFMA GRU ----
    if (act){
      #pragma unroll
      for (int m = 0; m < 4; m++){
        const int a_row = m*16 + c0;
        f16x8 as[4], ah[4];
        #pragma unroll
        for (int ks = 0; ks < 4; ks++){
          const float* sp = &s_l[a_row][ks*32 + 8*g];
          const float* hp = &h_l[a_row][ks*32 + 8*g];
          f16x8 av, bv;
          #pragma unroll
          for (int i2 = 0; i2 < 8; i2++){
            av[i2] = (_Float16)sp[i2];
            bv[i2] = (_Float16)hp[i2];
          }
          as[ks] = av; ah[ks] = bv;
        }
        f32x4 gi[3], gh[3];
        #pragma unroll
        for (int gate = 0; gate < 3; gate++){
          gi[gate] = (f32x4){0.f,0.f,0.f,0.f};
          gh[gate] = (f32x4){0.f,0.f,0.f,0.f};
        }
        #pragma unroll
        for (int gate = 0; gate < 3; gate++)
          #pragma unroll
          for (int ks = 0; ks < 4; ks++){
            gi[gate] = __builtin_amdgcn_mfma_f32_16x16x32_f16(as[ks], wcf[gate][ks], gi[gate], 0, 0, 0);
            gh[gate] = __builtin_amdgcn_mfma_f32_16x16x32_f16(ah[ks], whf[gate][ks], gh[gate], 0, 0, 0);
          }
        #pragma unroll
        for (int r = 0; r < 4; r++){
          const int node = m*16 + 4*g + r;
          const int v = vidx[node];
          if (v < 0) continue;
          const float dg = deg_l[node];
          float xr = 0.f, xz = 0.f, xn = 0.f;
          #pragma unroll
          for (int kx = 0; kx < 3; kx++){
            float xv = x_l[node][kx];
            xr = fmaf(wxv[0][kx], xv, xr);
            xz = fmaf(wxv[1][kx], xv, xz);
            xn = fmaf(wxv[2][kx], xv, xn);
          }
          float grv = gi[0][r] + biv[0] + dg*mbv[0] + xr + gh[0][r] + bhv[0];
          float gzv = gi[1][r] + biv[1] + dg*mbv[1] + xz + gh[1][r] + bhv[1];
          float rr = sigm(grv);
          float zz = sigm(gzv);
          float gnv = gi[2][r] + biv[2] + dg*mbv[2] + xn + rr*(gh[2][r] + bhv[2]);
          float nv = tanh_(gnv);
          float hv = h_l[node][jo];
          __hip_atomic_store(&h[(size_t)v*DD + jo], (1.f - zz)*nv + zz*hv,
                             __ATOMIC_RELAXED, __HIP_MEMORY_SCOPE_AGENT);
        }
      }
    }
    if (l < NLVL-1) gbar(bar, gen);   // level-l updates visible before level-l+1 gather
  }
}

// Persistent-weight MFMA MLP (round-5 kernel; now 2 blocks/CU)
__global__ __launch_bounds__(256, 2) void k_mlp_pw(const float* __restrict__ h,
    const _Float16* __restrict__ W1h, const float* __restrict__ b1,
    const _Float16* __restrict__ W2h, const float* __restrict__ b2,
    const float* __restrict__ W3, const float* __restrict__ b3,
    float* __restrict__ out){
  __shared__ _Float16 h1s[64*256];   // 32 KB, rows 512B, byte ^= (row&7)<<4
  __shared__ float red[4][64];
  const int t    = threadIdx.x;
  const int w    = t >> 6;
  const int lane = t & 63;
  const int c    = lane & 15;
  const int g    = lane >> 4;

  f16x8 w1f[4][4], w2f[4][8];
  #pragma unroll
  for (int n = 0; n < 4; n++){
    const _Float16* wp = W1h + ((4*w+n)*16 + c)*DD + 8*g;
    #pragma unroll
    for (int s = 0; s < 4; s++) w1f[n][s] = *(const f16x8*)(wp + s*32);
  }
  #pragma unroll
  for (int n = 0; n < 4; n++){
    const _Float16* wp = W2h + ((4*w+n)*16 + c)*DMM + 8*g;
    #pragma unroll
    for (int s = 0; s < 8; s++) w2f[n][s] = *(const f16x8*)(wp + s*32);
  }
  float bb1[4], bb2[4], w3v[4];
  #pragma unroll
  for (int n = 0; n < 4; n++){
    bb1[n] = b1[(4*w+n)*16 + c];
    bb2[n] = b2[(4*w+n)*16 + c];
    w3v[n] = W3[(4*w+n)*16 + c];
  }
  const float b3s = b3[0];

  for (int tile = blockIdx.x; tile < NN/64; tile += gridDim.x){
    const int base = tile*64;
    f16x8 a1[4][4];
    #pragma unroll
    for (int m = 0; m < 4; m++){
      const float* hp = h + (size_t)(base + m*16 + c)*DD + 8*g;
      #pragma unroll
      for (int s = 0; s < 4; s++){
        float4 u0 = *(const float4*)(hp + s*32);
        float4 u1 = *(const float4*)(hp + s*32 + 4);
        a1[m][s] = (f16x8){(_Float16)u0.x,(_Float16)u0.y,(_Float16)u0.z,(_Float16)u0.w,
                           (_Float16)u1.x,(_Float16)u1.y,(_Float16)u1.z,(_Float16)u1.w};
      }
    }
    f32x4 acc[4][4];
    #pragma unroll
    for (int m = 0; m < 4; m++)
      #pragma unroll
      for (int n = 0; n < 4; n++) acc[m][n] = (f32x4){0.f,0.f,0.f,0.f};
    #pragma unroll
    for (int m = 0; m < 4; m++)
      #pragma unroll
      for (int n = 0; n < 4; n++)
        #pragma unroll
        for (int s = 0; s < 4; s++)
          acc[m][n] = __builtin_amdgcn_mfma_f32_16x16x32_f16(a1[m][s], w1f[n][s], acc[m][n], 0, 0, 0);
    #pragma unroll
    for (int m = 0; m < 4; m++)
      #pragma unroll
      for (int n = 0; n < 4; n++)
        #pragma unroll
        for (int r = 0; r < 4; r++){
          int row = m*16 + 4*g + r;
          int off = (row*512 + ((4*w+n)*16 + c)*2) ^ ((row & 7) << 4);
          *(_Float16*)((char*)h1s + off) = (_Float16)fmaxf(acc[m][n][r] + bb1[n], 0.f);
        }
    __syncthreads();
    float p[4][4];
    #pragma unroll
    for (int m = 0; m < 4; m++)
      #pragma unroll
      for (int r = 0; r < 4; r++) p[m][r] = 0.f;
    #pragma unroll
    for (int m = 0; m < 4; m++){
      f16x8 a2[8];
      int row = m*16 + c;
      #pragma unroll
      for (int s = 0; s < 8; s++){
        int off = (row*512 + s*64 + g*16) ^ ((row & 7) << 4);
        a2[s] = *(const f16x8*)((const char*)h1s + off);
      }
      f32x4 acc2[4];
      #pragma unroll
      for (int n = 0; n < 4; n++) acc2[n] = (f32x4){0.f,0.f,0.f,0.f};
      #pragma unroll
      for (int n = 0; n < 4; n++)
        #pragma unroll
        for (int s = 0; s < 8; s++)
          acc2[n] = __builtin_amdgcn_mfma_f32_16x16x32_f16(a2[s], w2f[n][s], acc2[n], 0, 0, 0);
      #pragma unroll
      for (int n = 0; n < 4; n++)
        #pragma unroll
        for (int r = 0; r < 4; r++)
          p[m][r] = fmaf(fmaxf(acc2[n][r] + bb2[n], 0.f), w3v[n], p[m][r]);
    }
    #pragma unroll
    for (int msk = 1; msk < 16; msk <<= 1)
      #pragma unroll
      for (int m = 0; m < 4; m++)
        #pragma unroll
        for (int r = 0; r < 4; r++)
          p[m][r] += __shfl_xor(p[m][r], msk);
    if (c == 0){
      #pragma unroll
      for (int m = 0; m < 4; m++)
        #pragma unroll
        for (int r = 0; r < 4; r++)
          red[w][m*16 + 4*g + r] = p[m][r];
    }
    __syncthreads();
    if (t < 64)
      out[base + t] = red[0][t] + red[1][t] + red[2][t] + red[3][t] + b3s;
    __syncthreads();
  }
}

extern "C" void kernel_launch(void* const* d_in, const int* in_sizes, int n_in,
                              void* d_out, int out_size, void* d_ws, size_t ws_size,
                              hipStream_t stream){
  if (ws_size < (size_t)WS_NEEDED) return;  // fail validation cleanly, don't fault
  const float* x      = (const float*)d_in[0];
  const int*   ei     = (const int*)  d_in[1];
  const int*   srcp   = ei;
  const int*   dstp   = ei + NE;
  const int*   fl     = (const int*)  d_in[2];
  const float* W_emd  = (const float*)d_in[3];
  const float* b_emd  = (const float*)d_in[4];
  const float* W_aggr = (const float*)d_in[5];
  const float* b_aggr = (const float*)d_in[6];
  const float* w_ih   = (const float*)d_in[7];
  const float* w_hh   = (const float*)d_in[8];
  const float* b_ih   = (const float*)d_in[9];
  const float* b_hh   = (const float*)d_in[10];
  const float* W1     = (const float*)d_in[11];
  const float* b1     = (const float*)d_in[12];
  const float* W2     = (const float*)d_in[13];
  const float* b2     = (const float*)d_in[14];
  const float* W3     = (const float*)d_in[15];
  const float* b3     = (const float*)d_in[16];

  char* ws = (char*)d_ws;
  float* h        = (float*)(ws + OFF_H);
  int*   cso      = (int*)  (ws + OFF_CSO);
  int*   deg      = (int*)  (ws + OFF_DEG);
  int*   cur      = (int*)  (ws + OFF_CUR);
  int*   csr_src  = (int*)  (ws + OFF_CSRC);
  int*   bsum     = (int*)  (ws + OFF_BSUM);
  int*   node_list= (int*)  (ws + OFF_NLIST);
  _Float16* Wch   = (_Float16*)(ws + OFF_WCH);
  _Float16* whh_h = (_Float16*)(ws + OFF_WHH);
  float* mb       = (float*)(ws + OFF_MB);
  _Float16* W1h   = (_Float16*)(ws + OFF_W1H);
  _Float16* W2h   = (_Float16*)(ws + OFF_W2H);
  int*   cnt      = (int*)  (ws + OFF_CNT);
  float* outp     = (float*)d_out;

  const int nsb = (NN + SCB - 1)/SCB;   // 196 scan blocks

  hipMemsetAsync(ws + OFF_CNT, 0, 512, stream);
  hipMemsetAsync(ws + OFF_DEG, 0, 1600000, stream);   // deg + cur
  k_init_h<<<4096, 256, 0, stream>>>(h, W_emd, b_emd);
  k_count<<<1024, 256, 0, stream>>>(fl, cnt);
  k_scan<<<1, 64, 0, stream>>>(cnt);
  k_fill_n<<<196, 256, 0, stream>>>(fl, cnt, node_list);
  k_deg<<<1024, 256, 0, stream>>>(dstp, deg);
  k_cscan1<<<nsb, SCB, 0, stream>>>(deg, cso, bsum);
  k_cscan2<<<1, 64, 0, stream>>>(bsum, cso, nsb);
  k_cscan3<<<nsb, SCB, 0, stream>>>(cso, bsum);
  k_csr_fill<<<1024, 256, 0, stream>>>(srcp, dstp, cso, cur, csr_src);
  k_prep<<<256, 256, 0, stream>>>(w_ih, W_aggr, b_aggr, w_hh, W1, W2,
                                  Wch, whh_h, mb, W1h, W2h);
  k_levels<<<NBLK, 512, 0, stream>>>(cnt, node_list, cso, csr_src, x,
                                     Wch, whh_h, mb, w_ih, b_ih, b_hh, h,
                                     &cnt[120], &cnt[121]);
  k_mlp_pw<<<512, 256, 0, stream>>>(h, W1h, b1, W2h, b2, W3, b3, outp);
}

// Round 9
// 1106.472 us; speedup vs baseline: 3.2058x; 2.3852x over previous
//
#include <hip/hip_runtime.h>

#define NN 200000
#define NE 600000
#define DD 128
#define DXX 3
#define DMM 256
#define NLVL 16
#define NBLK 256

// ---- workspace byte offsets (total ~108.3 MB) ----
#define OFF_H      0LL                      // float h[NN][128]         102,400,000
#define OFF_CSO    102400000LL              // int csr_off[NN+1]            800,016
#define OFF_DEG    103200016LL              // int deg[NN]                  800,000
#define OFF_CUR    104000016LL              // int cur[NN]                  800,000
#define OFF_CSRC   104800016LL              // int csr_pack[NE]           2,400,000
#define OFF_BSUM   107200016LL              // int bsum[256]                  1,024
#define OFF_NLIST  107201040LL              // int node_list[NN]            800,000
#define OFF_WCH    108001040LL              // _Float16 Wch[384][128]        98,304
#define OFF_GHC    108099344LL              // float ghc[384]                 1,536
#define OFF_MB     108100880LL              // float mb[384]                  1,536
#define OFF_W1H    108102416LL              // _Float16 W1h[256][128]        65,536
#define OFF_W2H    108167952LL              // _Float16 W2h[256][256]       131,072
#define OFF_CNT    108299024LL              // int counters[128]                512
#define WS_NEEDED  108299536LL

// cnt layout: [0..15] node_cnt  [32..48] node_start(17)  [66..81] node_cur
//             [120] bar  [121] gen

typedef float    f32x4 __attribute__((ext_vector_type(4)));
typedef _Float16 f16x8 __attribute__((ext_vector_type(8)));

__device__ __forceinline__ float sigm(float x){
  x = fminf(fmaxf(x, -30.f), 30.f);
  return 1.f/(1.f + __expf(-x));
}
__device__ __forceinline__ float tanh_(float x){
  x = fminf(fmaxf(x, -15.f), 15.f);
  float e = __expf(2.f*x);
  return (e - 1.f)/(e + 1.f);
}

// h[v][d] = W_emd[d] + b_emd[d] for all v (fl=0 rows are read by gathers & MLP)
__global__ void k_init_h(float* h, const float* W_emd, const float* b_emd){
  __shared__ float h0[DD];
  if (threadIdx.x < DD) h0[threadIdx.x] = W_emd[threadIdx.x] + b_emd[threadIdx.x];
  __syncthreads();
  const int tot = NN*DD/4;
  for (int i = blockIdx.x*blockDim.x + threadIdx.x; i < tot; i += gridDim.x*blockDim.x){
    int d0 = (i & 31)*4;
    ((float4*)h)[i] = make_float4(h0[d0], h0[d0+1], h0[d0+2], h0[d0+3]);
  }
}

// histogram nodes by level
__global__ void k_count(const int* fl, int* cnt){
  __shared__ int hn[NLVL];
  if (threadIdx.x < NLVL) hn[threadIdx.x] = 0;
  __syncthreads();
  for (int i = blockIdx.x*blockDim.x + threadIdx.x; i < NN; i += gridDim.x*blockDim.x)
    atomicAdd(&hn[fl[i]], 1);
  __syncthreads();
  if (threadIdx.x < NLVL && hn[threadIdx.x])
    atomicAdd(&cnt[threadIdx.x], hn[threadIdx.x]);
}

__global__ void k_scan(int* cnt){
  if (threadIdx.x == 0){
    int s = 0;
    for (int l=0;l<NLVL;l++){ cnt[32+l] = s; s += cnt[l]; }
    cnt[48] = s;
    for (int l=0;l<NLVL;l++) cnt[66+l] = 0;
  }
}

// counting-sort fill of node_list (LDS hist + one global atomic per tile,level)
#define FB 1024
__global__ __launch_bounds__(256) void k_fill_n(const int* fl, int* cnt, int* node_list){
  __shared__ int hist[NLVL], base[NLVL];
  const int nt = (NN + FB - 1)/FB;
  for (int tile = blockIdx.x; tile < nt; tile += gridDim.x){
    const int i0 = tile*FB;
    if (threadIdx.x < NLVL) hist[threadIdx.x] = 0;
    __syncthreads();
    int lv[4], rk[4];
    #pragma unroll
    for (int j=0;j<4;j++){
      int i = i0 + threadIdx.x + j*256;
      if (i < NN){
        int l = fl[i];
        lv[j] = l;
        rk[j] = atomicAdd(&hist[l], 1);
      } else lv[j] = -1;
    }
    __syncthreads();
    if (threadIdx.x < NLVL)
      base[threadIdx.x] = atomicAdd(&cnt[66+threadIdx.x], hist[threadIdx.x]);
    __syncthreads();
    #pragma unroll
    for (int j=0;j<4;j++){
      if (lv[j] >= 0){
        int i = i0 + threadIdx.x + j*256;
        node_list[cnt[32+lv[j]] + base[lv[j]] + rk[j]] = i;
      }
    }
    __syncthreads();
  }
}

// in-degree count
__global__ void k_deg(const int* dst, int* deg){
  for (int e = blockIdx.x*blockDim.x + threadIdx.x; e < NE; e += gridDim.x*blockDim.x)
    atomicAdd(&deg[dst[e]], 1);
}

// 3-phase exclusive scan of deg -> csr_off
#define SCB 1024
__global__ __launch_bounds__(1024) void k_cscan1(const int* deg, int* cso, int* bsum){
  __shared__ int sh[SCB];
  const int b = blockIdx.x, t = threadIdx.x;
  const int i = b*SCB + t;
  int v = (i < NN) ? deg[i] : 0;
  sh[t] = v;
  __syncthreads();
  for (int ofs=1; ofs<SCB; ofs<<=1){
    int add = (t >= ofs) ? sh[t-ofs] : 0;
    __syncthreads();
    sh[t] += add;
    __syncthreads();
  }
  if (i < NN) cso[i] = sh[t] - v;   // exclusive
  if (t == SCB-1) bsum[b] = sh[t];
}
__global__ void k_cscan2(int* bsum, int* cso, int nb){
  if (threadIdx.x == 0){
    int run = 0;
    for (int b=0;b<nb;b++){ int tmp = bsum[b]; bsum[b] = run; run += tmp; }
    cso[NN] = run;
  }
}
__global__ __launch_bounds__(1024) void k_cscan3(int* cso, const int* bsum){
  const int i = blockIdx.x*SCB + threadIdx.x;
  if (i < NN) cso[i] += bsum[blockIdx.x];
}

// csr_pack[e] = src | (fl[src] << 24)
__global__ void k_csr_fill(const int* srcp, const int* dstp, const int* fl,
                           const int* cso, int* cur, int* csr_pack){
  for (int e = blockIdx.x*blockDim.x + threadIdx.x; e < NE; e += gridDim.x*blockDim.x){
    int d = dstp[e];
    int s = srcp[e];
    int p = atomicAdd(&cur[d], 1);
    csr_pack[cso[d] + p] = s | (fl[s] << 24);
  }
}

// Precompute: Wch = fp16(w_ih[:,:128] @ W_aggr) [384][128]; mb = w_ih[:,:128]@b_aggr;
// ghc = w_hh @ h0 + b_hh (exact f32; h0 = W_emd+b_emd); fp16 W1/W2.
__global__ void k_prep(const float* w_ih, const float* W_aggr, const float* b_aggr,
                       const float* w_hh, const float* W_emd, const float* b_emd,
                       const float* b_hh, const float* W1, const float* W2,
                       _Float16* Wch, float* ghc, float* mb,
                       _Float16* W1h, _Float16* W2h){
  const int tid = blockIdx.x*blockDim.x + threadIdx.x;
  const int stride = gridDim.x*blockDim.x;
  for (int i = tid; i < 384*DD; i += stride){
    int r = i >> 7, k = i & (DD-1);
    float s = 0.f;
    for (int j=0;j<DD;j++) s += w_ih[r*(DD+DXX)+j]*W_aggr[j*DD+k];
    Wch[i] = (_Float16)s;          // [r][k] row-major
  }
  for (int i = tid; i < 384; i += stride){
    float s = 0.f, gg = 0.f;
    for (int j=0;j<DD;j++){
      s  += w_ih[i*(DD+DXX)+j]*b_aggr[j];
      gg += w_hh[i*DD+j]*(W_emd[j] + b_emd[j]);
    }
    mb[i]  = s;
    ghc[i] = gg + b_hh[i];
  }
  for (int i = tid; i < DMM*DD;  i += stride) W1h[i] = (_Float16)W1[i];
  for (int i = tid; i < DMM*DMM; i += stride) W2h[i] = (_Float16)W2[i];
}

// device-wide barrier: RELAXED spin (no per-poll invalidate), one acquire on exit.
__device__ __forceinline__ void gbar(int* bar, int* gen){
  __syncthreads();
  if (threadIdx.x == 0){
    int g = __hip_atomic_load(gen, __ATOMIC_RELAXED, __HIP_MEMORY_SCOPE_AGENT);
    if (__hip_atomic_fetch_add(bar, 1, __ATOMIC_ACQ_REL, __HIP_MEMORY_SCOPE_AGENT) == NBLK-1){
      __hip_atomic_store(bar, 0, __ATOMIC_RELAXED, __HIP_MEMORY_SCOPE_AGENT);
      __hip_atomic_store(gen, g+1, __ATOMIC_RELEASE, __HIP_MEMORY_SCOPE_AGENT);
    } else {
      while (__hip_atomic_load(gen, __ATOMIC_RELAXED, __HIP_MEMORY_SCOPE_AGENT) == g)
        __builtin_amdgcn_s_sleep(8);
    }
  }
  __syncthreads();
  __builtin_amdgcn_fence(__ATOMIC_ACQUIRE, "agent");  // once per barrier, per wave
}

// ---- persistent level loop, MFMA GRU, no phase split, 14 barriers total.
// Own-state of an updating node is ALWAYS h0 -> gh = ghc (precomputed const).
// Gathered source s: state = h_final[s] iff 1<=fl[s]<l else h0 (no load).
// 512 thr / 8 waves; block owns ONE 64-node tile/level; wave w owns cols
// [16w,16w+16) of all 3 gates. Wch fragments persist in registers.
#define GT 64
__global__ __launch_bounds__(512, 1) void k_levels(const int* cnt,
    const int* node_list, const int* cso, const int* csr_pack,
    const float* x, const _Float16* Wch, const float* ghc, const float* mb,
    const float* w_ih, const float* b_ih, const float* W_emd, const float* b_emd,
    float* h, int* bar, int* gen){
  __shared__ float s_l[GT][DD+4];
  __shared__ float x_l[GT][4];
  __shared__ float deg_l[GT];
  __shared__ int   vidx[GT], eoff[GT], ecnt[GT];
  __shared__ float h0s[DD];
  const int t    = threadIdx.x;
  const int w    = t >> 6;
  const int lane = t & 63;
  const int c0   = lane & 15;
  const int g    = lane >> 4;
  const int jo   = w*16 + c0;

  if (t < DD) h0s[t] = W_emd[t] + b_emd[t];

  // persistent weight fragments + per-lane scalars
  f16x8 wcf[3][4];
  #pragma unroll
  for (int gate = 0; gate < 3; gate++){
    const _Float16* wp = Wch + (size_t)(gate*128 + jo)*DD + 8*g;
    #pragma unroll
    for (int ks = 0; ks < 4; ks++) wcf[gate][ks] = *(const f16x8*)(wp + ks*32);
  }
  float biv[3], mbv[3], ghcv[3], wxv[3][3];
  #pragma unroll
  for (int gate = 0; gate < 3; gate++){
    biv[gate]  = b_ih[gate*128 + jo];
    mbv[gate]  = mb[gate*128 + jo];
    ghcv[gate] = ghc[gate*128 + jo];
    #pragma unroll
    for (int kx = 0; kx < 3; kx++)
      wxv[gate][kx] = w_ih[(size_t)(gate*128 + jo)*(DD+DXX) + DD + kx];
  }
  const float h0v = W_emd[jo] + b_emd[jo];
  __syncthreads();

  for (int l = 1; l < NLVL; l++){
    const int n0 = cnt[32+l];
    const int na = cnt[32+l+1] - n0;
    const int tb = blockIdx.x * GT;
    const bool act = (tb < na);

    if (t < GT){
      int row = tb + t;
      int v = (act && row < na) ? node_list[n0 + row] : -1;
      vidx[t] = v;
      int e0 = 0, e1 = 0;
      if (v >= 0){ e0 = cso[v]; e1 = cso[v+1]; }
      eoff[t] = e0; ecnt[t] = e1 - e0;
      deg_l[t] = (float)(e1 - e0);
      for (int kx=0; kx<DXX; kx++) x_l[t][kx] = (v >= 0) ? x[v*DXX + kx] : 0.f;
    }
    __syncthreads();
    // gather: 8 threads/row, 16 dims each; load h only for updated sources
    {
      const int j = t >> 3, sub = t & 7;
      const int v = vidx[j];
      float4 a0={0,0,0,0}, a1={0,0,0,0}, a2={0,0,0,0}, a3={0,0,0,0};
      int nh0 = 0;
      if (v >= 0){
        const int e0 = eoff[j], n = ecnt[j];
        for (int i = 0; i < n; i++){
          int pk  = csr_pack[e0+i];
          int flv = pk >> 24;
          if (flv && flv < l){
            const float4* hs = (const float4*)(h + (size_t)(pk & 0xFFFFFF)*DD + sub*16);
            float4 c0v = hs[0], c1v = hs[1], c2v = hs[2], c3v = hs[3];
            a0.x+=c0v.x; a0.y+=c0v.y; a0.z+=c0v.z; a0.w+=c0v.w;
            a1.x+=c1v.x; a1.y+=c1v.y; a1.z+=c1v.z; a1.w+=c1v.w;
            a2.x+=c2v.x; a2.y+=c2v.y; a2.z+=c2v.z; a2.w+=c2v.w;
            a3.x+=c3v.x; a3.y+=c3v.y; a3.z+=c3v.z; a3.w+=c3v.w;
          } else nh0++;
        }
        if (nh0){
          float nh = (float)nh0;
          const float4* z = (const float4*)&h0s[sub*16];
          float4 z0=z[0], z1=z[1], z2=z[2], z3=z[3];
          a0.x+=nh*z0.x; a0.y+=nh*z0.y; a0.z+=nh*z0.z; a0.w+=nh*z0.w;
          a1.x+=nh*z1.x; a1.y+=nh*z1.y; a1.z+=nh*z1.z; a1.w+=nh*z1.w;
          a2.x+=nh*z2.x; a2.y+=nh*z2.y; a2.z+=nh*z2.z; a2.w+=nh*z2.w;
          a3.x+=nh*z3.x; a3.y+=nh*z3.y; a3.z+=nh*z3.z; a3.w+=nh*z3.w;
        }
      }
      *(float4*)&s_l[j][sub*16]      = a0;
      *(float4*)&s_l[j][sub*16 + 4]  = a1;
      *(float4*)&s_l[j][sub*16 + 8]  = a2;
      *(float4*)&s_l[j][sub*16 + 12] = a3;
    }
    __syncthreads();

    // MFMA GRU (gi only; gh == ghc const)
    if (act){
      #pragma unroll
      for (int m = 0; m < 4; m++){
        const int a_row = m*16 + c0;
        f16x8 as[4];
        #pragma unroll
        for (int ks = 0; ks < 4; ks++){
          const float* sp = &s_l[a_row][ks*32 + 8*g];
          f16x8 av;
          #pragma unroll
          for (int i2 = 0; i2 < 8; i2++) av[i2] = (_Float16)sp[i2];
          as[ks] = av;
        }
        f32x4 gi[3];
        #pragma unroll
        for (int gate = 0; gate < 3; gate++) gi[gate] = (f32x4){0.f,0.f,0.f,0.f};
        #pragma unroll
        for (int gate = 0; gate < 3; gate++)
          #pragma unroll
          for (int ks = 0; ks < 4; ks++)
            gi[gate] = __builtin_amdgcn_mfma_f32_16x16x32_f16(as[ks], wcf[gate][ks], gi[gate], 0, 0, 0);
        #pragma unroll
        for (int r = 0; r < 4; r++){
          const int node = m*16 + 4*g + r;
          const int v = vidx[node];
          if (v < 0) continue;
          const float dg = deg_l[node];
          float xr = 0.f, xz = 0.f, xn = 0.f;
          #pragma unroll
          for (int kx = 0; kx < 3; kx++){
            float xv = x_l[node][kx];
            xr = fmaf(wxv[0][kx], xv, xr);
            xz = fmaf(wxv[1][kx], xv, xz);
            xn = fmaf(wxv[2][kx], xv, xn);
          }
          float grv = gi[0][r] + biv[0] + dg*mbv[0] + xr + ghcv[0];
          float gzv = gi[1][r] + biv[1] + dg*mbv[1] + xz + ghcv[1];
          float rr = sigm(grv);
          float zz = sigm(gzv);
          float gnv = gi[2][r] + biv[2] + dg*mbv[2] + xn + rr*ghcv[2];
          float nv = tanh_(gnv);
          __hip_atomic_store(&h[(size_t)v*DD + jo], (1.f - zz)*nv + zz*h0v,
                             __ATOMIC_RELAXED, __HIP_MEMORY_SCOPE_AGENT);
        }
      }
    }
    if (l < NLVL-1) gbar(bar, gen);   // level-l updates visible before level-l+1 gather
  }
}

// Persistent-weight MFMA MLP (round-8 kernel)
__global__ __launch_bounds__(256, 2) void k_mlp_pw(const float* __restrict__ h,
    const _Float16* __restrict__ W1h, const float* __restrict__ b1,
    const _Float16* __restrict__ W2h, const float* __restrict__ b2,
    const float* __restrict__ W3, const float* __restrict__ b3,
    float* __restrict__ out){
  __shared__ _Float16 h1s[64*256];   // 32 KB, rows 512B, byte ^= (row&7)<<4
  __shared__ float red[4][64];
  const int t    = threadIdx.x;
  const int w    = t >> 6;
  const int lane = t & 63;
  const int c    = lane & 15;
  const int g    = lane >> 4;

  f16x8 w1f[4][4], w2f[4][8];
  #pragma unroll
  for (int n = 0; n < 4; n++){
    const _Float16* wp = W1h + ((4*w+n)*16 + c)*DD + 8*g;
    #pragma unroll
    for (int s = 0; s < 4; s++) w1f[n][s] = *(const f16x8*)(wp + s*32);
  }
  #pragma unroll
  for (int n = 0; n < 4; n++){
    const _Float16* wp = W2h + ((4*w+n)*16 + c)*DMM + 8*g;
    #pragma unroll
    for (int s = 0; s < 8; s++) w2f[n][s] = *(const f16x8*)(wp + s*32);
  }
  float bb1[4], bb2[4], w3v[4];
  #pragma unroll
  for (int n = 0; n < 4; n++){
    bb1[n] = b1[(4*w+n)*16 + c];
    bb2[n] = b2[(4*w+n)*16 + c];
    w3v[n] = W3[(4*w+n)*16 + c];
  }
  const float b3s = b3[0];

  for (int tile = blockIdx.x; tile < NN/64; tile += gridDim.x){
    const int base = tile*64;
    f16x8 a1[4][4];
    #pragma unroll
    for (int m = 0; m < 4; m++){
      const float* hp = h + (size_t)(base + m*16 + c)*DD + 8*g;
      #pragma unroll
      for (int s = 0; s < 4; s++){
        float4 u0 = *(const float4*)(hp + s*32);
        float4 u1 = *(const float4*)(hp + s*32 + 4);
        a1[m][s] = (f16x8){(_Float16)u0.x,(_Float16)u0.y,(_Float16)u0.z,(_Float16)u0.w,
                           (_Float16)u1.x,(_Float16)u1.y,(_Float16)u1.z,(_Float16)u1.w};
      }
    }
    f32x4 acc[4][4];
    #pragma unroll
    for (int m = 0; m < 4; m++)
      #pragma unroll
      for (int n = 0; n < 4; n++) acc[m][n] = (f32x4){0.f,0.f,0.f,0.f};
    #pragma unroll
    for (int m = 0; m < 4; m++)
      #pragma unroll
      for (int n = 0; n < 4; n++)
        #pragma unroll
        for (int s = 0; s < 4; s++)
          acc[m][n] = __builtin_amdgcn_mfma_f32_16x16x32_f16(a1[m][s], w1f[n][s], acc[m][n], 0, 0, 0);
    #pragma unroll
    for (int m = 0; m < 4; m++)
      #pragma unroll
      for (int n = 0; n < 4; n++)
        #pragma unroll
        for (int r = 0; r < 4; r++){
          int row = m*16 + 4*g + r;
          int off = (row*512 + ((4*w+n)*16 + c)*2) ^ ((row & 7) << 4);
          *(_Float16*)((char*)h1s + off) = (_Float16)fmaxf(acc[m][n][r] + bb1[n], 0.f);
        }
    __syncthreads();
    float p[4][4];
    #pragma unroll
    for (int m = 0; m < 4; m++)
      #pragma unroll
      for (int r = 0; r < 4; r++) p[m][r] = 0.f;
    #pragma unroll
    for (int m = 0; m < 4; m++){
      f16x8 a2[8];
      int row = m*16 + c;
      #pragma unroll
      for (int s = 0; s < 8; s++){
        int off = (row*512 + s*64 + g*16) ^ ((row & 7) << 4);
        a2[s] = *(const f16x8*)((const char*)h1s + off);
      }
      f32x4 acc2[4];
      #pragma unroll
      for (int n = 0; n < 4; n++) acc2[n] = (f32x4){0.f,0.f,0.f,0.f};
      #pragma unroll
      for (int n = 0; n < 4; n++)
        #pragma unroll
        for (int s = 0; s < 8; s++)
          acc2[n] = __builtin_amdgcn_mfma_f32_16x16x32_f16(a2[s], w2f[n][s], acc2[n], 0, 0, 0);
      #pragma unroll
      for (int n = 0; n < 4; n++)
        #pragma unroll
        for (int r = 0; r < 4; r++)
          p[m][r] = fmaf(fmaxf(acc2[n][r] + bb2[n], 0.f), w3v[n], p[m][r]);
    }
    #pragma unroll
    for (int msk = 1; msk < 16; msk <<= 1)
      #pragma unroll
      for (int m = 0; m < 4; m++)
        #pragma unroll
        for (int r = 0; r < 4; r++)
          p[m][r] += __shfl_xor(p[m][r], msk);
    if (c == 0){
      #pragma unroll
      for (int m = 0; m < 4; m++)
        #pragma unroll
        for (int r = 0; r < 4; r++)
          red[w][m*16 + 4*g + r] = p[m][r];
    }
    __syncthreads();
    if (t < 64)
      out[base + t] = red[0][t] + red[1][t] + red[2][t] + red[3][t] + b3s;
    __syncthreads();
  }
}

extern "C" void kernel_launch(void* const* d_in, const int* in_sizes, int n_in,
                              void* d_out, int out_size, void* d_ws, size_t ws_size,
                              hipStream_t stream){
  if (ws_size < (size_t)WS_NEEDED) return;  // fail validation cleanly, don't fault
  const float* x      = (const float*)d_in[0];
  const int*   ei     = (const int*)  d_in[1];
  const int*   srcp   = ei;
  const int*   dstp   = ei + NE;
  const int*   fl     = (const int*)  d_in[2];
  const float* W_emd  = (const float*)d_in[3];
  const float* b_emd  = (const float*)d_in[4];
  const float* W_aggr = (const float*)d_in[5];
  const float* b_aggr = (const float*)d_in[6];
  const float* w_ih   = (const float*)d_in[7];
  const float* w_hh   = (const float*)d_in[8];
  const float* b_ih   = (const float*)d_in[9];
  const float* b_hh   = (const float*)d_in[10];
  const float* W1     = (const float*)d_in[11];
  const float* b1     = (const float*)d_in[12];
  const float* W2     = (const float*)d_in[13];
  const float* b2     = (const float*)d_in[14];
  const float* W3     = (const float*)d_in[15];
  const float* b3     = (const float*)d_in[16];

  char* ws = (char*)d_ws;
  float* h        = (float*)(ws + OFF_H);
  int*   cso      = (int*)  (ws + OFF_CSO);
  int*   deg      = (int*)  (ws + OFF_DEG);
  int*   cur      = (int*)  (ws + OFF_CUR);
  int*   csr_pack = (int*)  (ws + OFF_CSRC);
  int*   bsum     = (int*)  (ws + OFF_BSUM);
  int*   node_list= (int*)  (ws + OFF_NLIST);
  _Float16* Wch   = (_Float16*)(ws + OFF_WCH);
  float* ghc      = (float*)(ws + OFF_GHC);
  float* mb       = (float*)(ws + OFF_MB);
  _Float16* W1h   = (_Float16*)(ws + OFF_W1H);
  _Float16* W2h   = (_Float16*)(ws + OFF_W2H);
  int*   cnt      = (int*)  (ws + OFF_CNT);
  float* outp     = (float*)d_out;

  const int nsb = (NN + SCB - 1)/SCB;   // 196 scan blocks

  hipMemsetAsync(ws + OFF_CNT, 0, 512, stream);
  hipMemsetAsync(ws + OFF_DEG, 0, 1600000, stream);   // deg + cur
  k_init_h<<<4096, 256, 0, stream>>>(h, W_emd, b_emd);
  k_count<<<1024, 256, 0, stream>>>(fl, cnt);
  k_scan<<<1, 64, 0, stream>>>(cnt);
  k_fill_n<<<196, 256, 0, stream>>>(fl, cnt, node_list);
  k_deg<<<1024, 256, 0, stream>>>(dstp, deg);
  k_cscan1<<<nsb, SCB, 0, stream>>>(deg, cso, bsum);
  k_cscan2<<<1, 64, 0, stream>>>(bsum, cso, nsb);
  k_cscan3<<<nsb, SCB, 0, stream>>>(cso, bsum);
  k_csr_fill<<<1024, 256, 0, stream>>>(srcp, dstp, fl, cso, cur, csr_pack);
  k_prep<<<256, 256, 0, stream>>>(w_ih, W_aggr, b_aggr, w_hh, W_emd, b_emd, b_hh,
                                  W1, W2, Wch, ghc, mb, W1h, W2h);
  k_levels<<<NBLK, 512, 0, stream>>>(cnt, node_list, cso, csr_pack, x,
                                     Wch, ghc, mb, w_ih, b_ih, W_emd, b_emd, h,
                                     &cnt[120], &cnt[121]);
  k_mlp_pw<<<512, 256, 0, stream>>>(h, W1h, b1, W2h, b2, W3, b3, outp);
}